// Round 10
// baseline (458.012 us; speedup 1.0000x reference)
//
#include <hip/hip_runtime.h>
#include <hip/hip_cooperative_groups.h>
namespace cg = cooperative_groups;

#define BINS 5
#define PTS  2
constexpr int Bx = 2, Cc = 256, Hh = 100, Ww = 152;
constexpr int HW = Hh * Ww;          // 15200
constexpr int NTILE = 475;           // 32-px tiles (exact)
constexpr float EPS_DIV = 1e-6f;
constexpr float GN_EPS  = 1e-5f;

typedef __attribute__((ext_vector_type(8)))  _Float16 hfrag;  // 8 fp16
typedef __attribute__((ext_vector_type(2)))  _Float16 h2;
typedef __attribute__((ext_vector_type(16))) float    f32x16; // 32x32 MFMA C/D

__device__ __forceinline__ ushort f2h(float f) {
    return __builtin_bit_cast(ushort, (_Float16)f);
}
__device__ __forceinline__ float hlo(unsigned u) {
    return (float)__builtin_bit_cast(_Float16, (ushort)(u & 0xffffu));
}
__device__ __forceinline__ float hhi(unsigned u) {
    return (float)__builtin_bit_cast(_Float16, (ushort)(u >> 16));
}

#define GLL16(g, l) __builtin_amdgcn_global_load_lds( \
    (const __attribute__((address_space(1))) unsigned*)(g), \
    (__attribute__((address_space(3))) unsigned*)(l), 16, 0, 0)

#define MFMA32(a, b, c) __builtin_amdgcn_mfma_f32_32x32x16_f16(a, b, c, 0, 0, 0)
#define SB0() __builtin_amdgcn_sched_barrier(0)

// ---------------------------------------------------------------------------
// K0: fused preprocessing (weights -> fp16 frag order; x transpose) (proven)
// ---------------------------------------------------------------------------
__global__ __launch_bounds__(256)
void k_pre(const float* __restrict__ efw, const float* __restrict__ w1,
           const float* __restrict__ mw, ushort* __restrict__ wb,
           const float* __restrict__ x, ushort* __restrict__ xbt)
{
    __shared__ float tile[32][33];
    const int bid = blockIdx.x;
    const int t = threadIdx.x;
    if (bid < 192) {
        int gid = bid * 256 + t;
        int i = gid * 8;
        int arr = i >> 17, off = i & 131071;
        const float* src = arr == 0 ? efw : (arr == 1 ? w1 : mw);
        float4 v0 = *(const float4*)(src + off);
        float4 v1 = *(const float4*)(src + off + 4);
        int outaddr;
        if (arr == 0) {                // ef_w: M=512, K=256
            int m = off >> 8, k = off & 255;
            outaddr = (((k >> 4) * 16 + (m >> 5)) * 64 + (m & 31) + 32 * ((k >> 3) & 1)) * 8;
        } else if (arr == 1) {         // hm1_w: per p, M=256, K=256
            int p = off >> 16, r = off & 65535;
            int m = r >> 8, k = r & 255;
            outaddr = p * 65536 +
                      (((k >> 4) * 8 + (m >> 5)) * 64 + (m & 31) + 32 * ((k >> 3) & 1)) * 8;
        } else {                       // merge_w: M=256, K=512
            int m = off >> 9, k = off & 511;
            outaddr = (((k >> 4) * 8 + (m >> 5)) * 64 + (m & 31) + 32 * ((k >> 3) & 1)) * 8;
        }
        ushort o[8] = { f2h(v0.x), f2h(v0.y), f2h(v0.z), f2h(v0.w),
                        f2h(v1.x), f2h(v1.y), f2h(v1.z), f2h(v1.w) };
        *(uint4*)(wb + arr * 131072 + outaddr) = *(uint4*)o;
    } else {
        int r = bid - 192;             // 0..7599
        const int b = r / 3800; r -= b * 3800;
        const int c0 = (r / 475) * 32;
        const int hw0 = (r % 475) * 32;
        const float* xb = x + ((size_t)b * Cc + c0) * HW + hw0;
        const int tx = t & 31, ty = t >> 5;
        #pragma unroll
        for (int rr = 0; rr < 4; rr++) {
            int c = ty + rr * 8;
            tile[c][tx] = xb[(size_t)c * HW + tx];
        }
        __syncthreads();
        const int hwl = t >> 3, c4 = (t & 7) * 4;
        ushort4 o = { f2h(tile[c4 + 0][hwl]), f2h(tile[c4 + 1][hwl]),
                      f2h(tile[c4 + 2][hwl]), f2h(tile[c4 + 3][hwl]) };
        *(ushort4*)&xbt[((size_t)b * HW + hw0 + hwl) * Cc + c0 + c4] = o;
    }
}

// ---------------------------------------------------------------------------
// K1: efp = ef_w @ x + ef_b (proven R3)
// ---------------------------------------------------------------------------
__global__ __launch_bounds__(512, 2)
void k_ef(const ushort* __restrict__ xbt, const ushort* __restrict__ wbe,
          const float* __restrict__ efb, ushort* __restrict__ efp)
{
    __shared__ ushort B0[64 * 256];
    __shared__ ushort B1[64 * 256];
    const int t = threadIdx.x;
    const int wv = t >> 6, ln = t & 63;
    const int l31 = ln & 31, lh = ln >> 5;
    const int b = blockIdx.y;
    const int tt0 = blockIdx.x * 2;
    const ushort* xb = xbt + (size_t)b * HW * Cc;

    hfrag A[2][16];
    #pragma unroll
    for (int mf = 0; mf < 2; mf++)
        #pragma unroll
        for (int ks = 0; ks < 16; ks++)
            A[mf][ks] = *(const hfrag*)&wbe[((ks * 16 + (wv * 2 + mf)) * 64 + ln) * 8];
    SB0();

    auto stageB = [&](int tt, ushort* dst) {
        int tp0 = tt * 64;
        #pragma unroll
        for (int j = 0; j < 4; j++) {
            int unit = j * 512 + t;
            int prow = unit >> 5, c8 = unit & 31;
            int pq = tp0 + prow; if (pq > HW - 1) pq = HW - 1;
            const ushort* g = xb + (size_t)pq * Cc + ((c8 ^ (prow & 7)) << 3);
            ushort* l = dst + (j * 512 + wv * 64) * 8;
            GLL16(g, l);
        }
    };
    stageB(tt0, B0);
    stageB(tt0 + 1, B1);
    SB0();
    asm volatile("s_waitcnt vmcnt(4)" ::: "memory");
    __builtin_amdgcn_s_barrier();
    SB0();

    auto compute = [&](int tt, const ushort* Bs) {
        f32x16 acc[2][2];
        #pragma unroll
        for (int mf = 0; mf < 2; mf++)
            #pragma unroll
            for (int pf = 0; pf < 2; pf++)
                #pragma unroll
                for (int r = 0; r < 16; r++) acc[mf][pf][r] = 0.f;
        #pragma unroll
        for (int ks = 0; ks < 16; ks++) {
            int c = ks * 2 + lh;
            #pragma unroll
            for (int pf = 0; pf < 2; pf++) {
                hfrag bf = *(const hfrag*)&Bs[(pf * 32 + l31) * 256 + ((c ^ (l31 & 7)) << 3)];
                acc[0][pf] = MFMA32(A[0][ks], bf, acc[0][pf]);
                acc[1][pf] = MFMA32(A[1][ks], bf, acc[1][pf]);
            }
        }
        const int tp0 = tt * 64;
        #pragma unroll
        for (int mf = 0; mf < 2; mf++) {
            int m0 = wv * 2 + mf;
            const int p_ = m0 >> 3;
            ushort* outb = efp + (size_t)((b * PTS + p_) * HW) * Cc;
            int chb = (m0 * 32) & 255;
            #pragma unroll
            for (int q = 0; q < 4; q++) {
                float4 bv = *(const float4*)&efb[m0 * 32 + q * 8 + 4 * lh];
                #pragma unroll
                for (int pf = 0; pf < 2; pf++) {
                    int px = tp0 + pf * 32 + l31;
                    if (px < HW) {
                        int ch = chb + q * 8 + 4 * lh;
                        ushort4 o = { f2h(acc[mf][pf][q * 4 + 0] + bv.x),
                                      f2h(acc[mf][pf][q * 4 + 1] + bv.y),
                                      f2h(acc[mf][pf][q * 4 + 2] + bv.z),
                                      f2h(acc[mf][pf][q * 4 + 3] + bv.w) };
                        *(ushort4*)&outb[(size_t)px * Cc + ch] = o;
                    }
                }
            }
        }
    };
    compute(tt0, B0);
    asm volatile("s_waitcnt vmcnt(0)" ::: "memory");
    __builtin_amdgcn_s_barrier();
    SB0();
    compute(tt0 + 1, B1);
}

// ---------------------------------------------------------------------------
// K2: heat = exp(w2.relu(w1@efp + b1) + b2) fused (proven R3)
// ---------------------------------------------------------------------------
__global__ __launch_bounds__(512, 2)
void k_heat(const ushort* __restrict__ efp, const ushort* __restrict__ wb1,
            const float* __restrict__ b1, const float* __restrict__ w2,
            const float* __restrict__ b2, float* __restrict__ heat)
{
    __shared__ ushort B0[64 * 256];
    __shared__ ushort B1[64 * 256];
    __shared__ float red[8][64];
    const int t = threadIdx.x;
    const int wv = t >> 6, ln = t & 63;
    const int l31 = ln & 31, lh = ln >> 5;
    const int zz = blockIdx.y;
    const int b = zz >> 1, p = zz & 1;
    const int tt0 = blockIdx.x * 2;
    const ushort* eb = efp + (size_t)((b * PTS + p) * HW) * Cc;
    const float* b1p = b1 + p * 256;
    const float* w2p = w2 + p * 256;
    const float b2v = b2[p];

    hfrag A[16];
    #pragma unroll
    for (int ks = 0; ks < 16; ks++)
        A[ks] = *(const hfrag*)&wb1[p * 65536 + ((ks * 8 + wv) * 64 + ln) * 8];
    SB0();

    auto stageB = [&](int tt, ushort* dst) {
        int tp0 = tt * 64;
        #pragma unroll
        for (int j = 0; j < 4; j++) {
            int unit = j * 512 + t;
            int prow = unit >> 5, c8 = unit & 31;
            int pq = tp0 + prow; if (pq > HW - 1) pq = HW - 1;
            const ushort* g = eb + (size_t)pq * Cc + ((c8 ^ (prow & 7)) << 3);
            ushort* l = dst + (j * 512 + wv * 64) * 8;
            GLL16(g, l);
        }
    };
    stageB(tt0, B0);
    stageB(tt0 + 1, B1);
    SB0();
    asm volatile("s_waitcnt vmcnt(4)" ::: "memory");
    __builtin_amdgcn_s_barrier();
    SB0();

    auto compute = [&](int tt, const ushort* Bs) {
        f32x16 acc[2];
        #pragma unroll
        for (int pf = 0; pf < 2; pf++)
            #pragma unroll
            for (int r = 0; r < 16; r++) acc[pf][r] = 0.f;
        #pragma unroll
        for (int ks = 0; ks < 16; ks++) {
            int c = ks * 2 + lh;
            #pragma unroll
            for (int pf = 0; pf < 2; pf++) {
                hfrag bf = *(const hfrag*)&Bs[(pf * 32 + l31) * 256 + ((c ^ (l31 & 7)) << 3)];
                acc[pf] = MFMA32(A[ks], bf, acc[pf]);
            }
        }
        float s[2] = {0.f, 0.f};
        #pragma unroll
        for (int q = 0; q < 4; q++) {
            float4 b1v = *(const float4*)&b1p[wv * 32 + q * 8 + 4 * lh];
            float4 w2v = *(const float4*)&w2p[wv * 32 + q * 8 + 4 * lh];
            #pragma unroll
            for (int pf = 0; pf < 2; pf++) {
                float h0 = acc[pf][q * 4 + 0] + b1v.x;
                float h1 = acc[pf][q * 4 + 1] + b1v.y;
                float h2_ = acc[pf][q * 4 + 2] + b1v.z;
                float h3 = acc[pf][q * 4 + 3] + b1v.w;
                s[pf] += w2v.x * (h0 > 0.f ? h0 : 0.f);
                s[pf] += w2v.y * (h1 > 0.f ? h1 : 0.f);
                s[pf] += w2v.z * (h2_ > 0.f ? h2_ : 0.f);
                s[pf] += w2v.w * (h3 > 0.f ? h3 : 0.f);
            }
        }
        s[0] += __shfl_xor(s[0], 32);
        s[1] += __shfl_xor(s[1], 32);
        if (lh == 0) {
            red[wv][l31]      = s[0];
            red[wv][32 + l31] = s[1];
        }
        asm volatile("s_waitcnt lgkmcnt(0)" ::: "memory");
        __builtin_amdgcn_s_barrier();
        if (t < 64) {
            float v = red[0][t] + red[1][t] + red[2][t] + red[3][t] +
                      red[4][t] + red[5][t] + red[6][t] + red[7][t];
            int px = tt * 64 + t;
            if (px < HW) heat[(size_t)(b * PTS + p) * HW + px] = expf(v + b2v);
        }
    };
    compute(tt0, B0);
    asm volatile("s_waitcnt vmcnt(0)" ::: "memory");
    __builtin_amdgcn_s_barrier();
    SB0();
    compute(tt0 + 1, B1);
}

// ---------------------------------------------------------------------------
// K3 (cooperative): sampling + merge + GN stats + GN apply in ONE kernel.
// Blocks keep their merged tile in registers across two grid syncs, so the
// mgb round-trip (31 MB) and two launches disappear.  Idle blocks (tile 475)
// stay alive for the syncs.  LDS 40448 -> 4 blocks/CU -> 1024 >= 952 blocks.
// ---------------------------------------------------------------------------
__global__ __launch_bounds__(512, 8)
void k_smgn(const ushort* __restrict__ efp, const float* __restrict__ heat,
            const float* __restrict__ offs, const ushort* __restrict__ wbm,
            const float* __restrict__ mb, const float* __restrict__ gg,
            const float* __restrict__ gb, float* __restrict__ part2,
            float* __restrict__ statf, float* __restrict__ out)
{
    __shared__ ushort Bs[32 * 512];       // 32768 B sampled tile [px][512]
    __shared__ unsigned s_w[2][32][20];   // 5120 B
    __shared__ ushort   s_o[2][32][20];   // 2560 B
    const int t = threadIdx.x;
    const int wv = t >> 6, ln = t & 63;
    const int l31 = ln & 31, lh = ln >> 5;
    const int bid = blockIdx.x;
    const int xcd = bid & 7, ii = bid >> 3;          // ii in 0..118
    const int b = xcd >> 2;
    const int tile = (xcd & 3) * 119 + ii;
    const bool active = (tile < NTILE);              // 2 idle blocks keep syncing
    const int m0 = tile * 32;

    f32x16 acc;
    #pragma unroll
    for (int r = 0; r < 16; r++) acc[r] = 0.f;

    if (active) {
        // ---- phase 1: bilinear weights for both p (320 threads) ----
        if (t < 32 * BINS * PTS) {
            int p = t / 160, r = t - p * 160;
            int j = r / BINS, k = r - (r / BINS) * BINS;
            int hw = m0 + j;
            int hh = hw / Ww, ww = hw - hh * Ww;
            const float* heat_bp = heat + (size_t)(b * PTS + p) * HW;
            int chy = (p * BINS + k) * 2;
            float oy = offs[((size_t)b * (PTS * BINS * 2) + chy)     * HW + hw];
            float ox = offs[((size_t)b * (PTS * BINS * 2) + chy + 1) * HW + hw];
            float ysf = (float)hh + oy;
            float xsf = (float)ww + ox;
            float y0 = floorf(ysf), x0 = floorf(xsf);
            #pragma unroll
            for (int dy = 0; dy < 2; dy++)
                #pragma unroll
                for (int dx = 0; dx < 2; dx++) {
                    float yi = y0 + dy, xi = x0 + dx;
                    float wgt = (1.f - fabsf(ysf - yi)) * (1.f - fabsf(xsf - xi));
                    bool valid = (yi >= 0.f) && (yi <= (float)(Hh - 1)) &&
                                 (xi >= 0.f) && (xi <= (float)(Ww - 1));
                    int yc = (int)yi; yc = yc < 0 ? 0 : (yc > Hh - 1 ? Hh - 1 : yc);
                    int xc = (int)xi; xc = xc < 0 ? 0 : (xc > Ww - 1 ? Ww - 1 : xc);
                    int idx = yc * Ww + xc;
                    float wh = valid ? wgt * heat_bp[idx] : 0.f;
                    int slot = k * 4 + dy * 2 + dx;
                    s_w[p][j][slot] = __float_as_uint(wh);
                    s_o[p][j][slot] = (ushort)idx;
                }
        }
        __syncthreads();
        // ---- phase 2: normalize + pack fp16 pair (64 threads) ----
        if (t < 64) {
            int p = t >> 5, px = t & 31;
            float s = 0.f;
            #pragma unroll
            for (int u = 0; u < 20; u++) s += __uint_as_float(s_w[p][px][u]);
            float inv = 1.f / (s + EPS_DIV);
            #pragma unroll
            for (int u = 0; u < 20; u++) {
                float w = __uint_as_float(s_w[p][px][u]) * inv;
                unsigned hw16 = (unsigned)f2h(w);
                s_w[p][px][u] = hw16 | (hw16 << 16);
            }
        }
        __syncthreads();

        // ---- phase 3: gather (proven R8 form; VGPR-safe for 8 waves/EU) ----
        {
            const int p = wv >> 2;
            const int jb = (wv & 3) * 8;
            const int g = p * 32 + l31;
            const char* efbase = (const char*)(efp + (size_t)((b * PTS + p) * HW) * Cc)
                                 + l31 * 16;
            #pragma unroll
            for (int i2 = 0; i2 < 8; i2 += 2) {
                const int j = jb + i2 + lh;
                h2 a0 = (h2){0, 0}, a1 = (h2){0, 0}, a2 = (h2){0, 0}, a3 = (h2){0, 0};
                #pragma unroll
                for (int u = 0; u < 20; u++) {
                    unsigned wu = s_w[p][j][u];
                    unsigned idx = s_o[p][j][u];
                    uint4 v = *(const uint4*)(efbase + ((size_t)idx << 9));
                    h2 wp = __builtin_bit_cast(h2, wu);
                    a0 += wp * __builtin_bit_cast(h2, v.x);
                    a1 += wp * __builtin_bit_cast(h2, v.y);
                    a2 += wp * __builtin_bit_cast(h2, v.z);
                    a3 += wp * __builtin_bit_cast(h2, v.w);
                }
                uint4 o = { __builtin_bit_cast(unsigned, a0), __builtin_bit_cast(unsigned, a1),
                            __builtin_bit_cast(unsigned, a2), __builtin_bit_cast(unsigned, a3) };
                *(uint4*)&Bs[j * 512 + ((g ^ j) << 3)] = o;
            }
        }
        __syncthreads();

        // ---- phase 4: merge GEMM; bias into acc; GN partials ----
        #pragma unroll 1
        for (int c4 = 0; c4 < 4; c4++) {
            hfrag A8[8];
            #pragma unroll
            for (int k8 = 0; k8 < 8; k8++)
                A8[k8] = *(const hfrag*)&wbm[(((c4 * 8 + k8) * 8 + wv) * 64 + ln) * 8];
            #pragma unroll
            for (int k8 = 0; k8 < 8; k8++) {
                int c = (c4 * 8 + k8) * 2 + lh;
                hfrag bf = *(const hfrag*)&Bs[l31 * 512 + ((c ^ l31) << 3)];
                acc = MFMA32(A8[k8], bf, acc);
            }
        }
        float sg[4] = {0.f, 0.f, 0.f, 0.f};
        float qg[4] = {0.f, 0.f, 0.f, 0.f};
        #pragma unroll
        for (int q = 0; q < 4; q++) {
            float4 bv = *(const float4*)&mb[wv * 32 + q * 8 + 4 * lh];
            #pragma unroll
            for (int r = 0; r < 4; r++) {
                float bb = r == 0 ? bv.x : (r == 1 ? bv.y : (r == 2 ? bv.z : bv.w));
                acc[q * 4 + r] += bb;
                float v = acc[q * 4 + r];
                sg[q] += v; qg[q] += v * v;
            }
        }
        #pragma unroll
        for (int q = 0; q < 4; q++) {
            #pragma unroll
            for (int off = 1; off <= 32; off <<= 1) {
                sg[q] += __shfl_xor(sg[q], off);
                qg[q] += __shfl_xor(qg[q], off);
            }
        }
        if (ln == 0) {
            #pragma unroll
            for (int q = 0; q < 4; q++) {
                int g = wv * 4 + q;
                size_t idx = ((size_t)(b * 32 + g) * NTILE + tile) * 2;
                part2[idx + 0] = sg[q];
                part2[idx + 1] = qg[q];
            }
        }
    }

    cg::this_grid().sync();

    // ---- stats: blocks 0..63 reduce part2 -> statf ----
    if (bid < 64) {
        float s = 0.f, q = 0.f;
        for (int u = t; u < NTILE; u += 512) {
            s += part2[((size_t)bid * NTILE + u) * 2 + 0];
            q += part2[((size_t)bid * NTILE + u) * 2 + 1];
        }
        #pragma unroll
        for (int off = 1; off <= 32; off <<= 1) {
            s += __shfl_xor(s, off);
            q += __shfl_xor(q, off);
        }
        float* red = (float*)Bs;
        if (ln == 0) { red[wv * 2] = s; red[wv * 2 + 1] = q; }
        __syncthreads();
        if (t == 0) {
            float S = 0.f, Q = 0.f;
            #pragma unroll
            for (int w = 0; w < 8; w++) { S += red[w * 2]; Q += red[w * 2 + 1]; }
            const float n = 8.f * HW;
            float mean = S / n;
            float var  = Q / n - mean * mean;
            statf[bid * 2 + 0] = mean;
            statf[bid * 2 + 1] = rsqrtf(var + GN_EPS);
        }
    }

    cg::this_grid().sync();

    // ---- apply GN + ReLU from register-held acc; write fp32 out ----
    if (active) {
        const int px = m0 + l31;
        #pragma unroll
        for (int q = 0; q < 4; q++) {
            int g = wv * 4 + q;
            float mean = statf[(b * 32 + g) * 2 + 0];
            float istd = statf[(b * 32 + g) * 2 + 1];
            #pragma unroll
            for (int r = 0; r < 4; r++) {
                int ch = wv * 32 + q * 8 + 4 * lh + r;
                float sc = istd * gg[ch];
                float sh = gb[ch] - mean * sc;
                out[((size_t)b * Cc + ch) * HW + px] =
                    fmaxf(acc[q * 4 + r] * sc + sh, 0.f);
            }
        }
    }
}

// ---------------------------------------------------------------------------
// Fallback path (R9-proven): k_sm + k_gnfinal + k_gnapply, used only if the
// cooperative launch is rejected.
// ---------------------------------------------------------------------------
__global__ __launch_bounds__(512, 8)
void k_sm(const ushort* __restrict__ efp, const float* __restrict__ heat,
          const float* __restrict__ offs, const ushort* __restrict__ wbm,
          const float* __restrict__ mb, ushort* __restrict__ mgb,
          float* __restrict__ part2)
{
    __shared__ ushort Bs[32 * 512];
    __shared__ unsigned s_w[2][32][20];
    __shared__ ushort   s_o[2][32][20];
    const int t = threadIdx.x;
    const int wv = t >> 6, ln = t & 63;
    const int l31 = ln & 31, lh = ln >> 5;
    const int bid = blockIdx.x;
    const int xcd = bid & 7, ii = bid >> 3;
    const int b = xcd >> 2;
    const int tile = (xcd & 3) * 119 + ii;
    if (tile >= NTILE) return;
    const int m0 = tile * 32;

    if (t < 32 * BINS * PTS) {
        int p = t / 160, r = t - p * 160;
        int j = r / BINS, k = r - (r / BINS) * BINS;
        int hw = m0 + j;
        int hh = hw / Ww, ww = hw - hh * Ww;
        const float* heat_bp = heat + (size_t)(b * PTS + p) * HW;
        int chy = (p * BINS + k) * 2;
        float oy = offs[((size_t)b * (PTS * BINS * 2) + chy)     * HW + hw];
        float ox = offs[((size_t)b * (PTS * BINS * 2) + chy + 1) * HW + hw];
        float ysf = (float)hh + oy;
        float xsf = (float)ww + ox;
        float y0 = floorf(ysf), x0 = floorf(xsf);
        #pragma unroll
        for (int dy = 0; dy < 2; dy++)
            #pragma unroll
            for (int dx = 0; dx < 2; dx++) {
                float yi = y0 + dy, xi = x0 + dx;
                float wgt = (1.f - fabsf(ysf - yi)) * (1.f - fabsf(xsf - xi));
                bool valid = (yi >= 0.f) && (yi <= (float)(Hh - 1)) &&
                             (xi >= 0.f) && (xi <= (float)(Ww - 1));
                int yc = (int)yi; yc = yc < 0 ? 0 : (yc > Hh - 1 ? Hh - 1 : yc);
                int xc = (int)xi; xc = xc < 0 ? 0 : (xc > Ww - 1 ? Ww - 1 : xc);
                int idx = yc * Ww + xc;
                float wh = valid ? wgt * heat_bp[idx] : 0.f;
                int slot = k * 4 + dy * 2 + dx;
                s_w[p][j][slot] = __float_as_uint(wh);
                s_o[p][j][slot] = (ushort)idx;
            }
    }
    __syncthreads();
    if (t < 64) {
        int p = t >> 5, px = t & 31;
        float s = 0.f;
        #pragma unroll
        for (int u = 0; u < 20; u++) s += __uint_as_float(s_w[p][px][u]);
        float inv = 1.f / (s + EPS_DIV);
        #pragma unroll
        for (int u = 0; u < 20; u++) {
            float w = __uint_as_float(s_w[p][px][u]) * inv;
            unsigned hw16 = (unsigned)f2h(w);
            s_w[p][px][u] = hw16 | (hw16 << 16);
        }
    }
    __syncthreads();
    {
        const int p = wv >> 2;
        const int jb = (wv & 3) * 8;
        const int g = p * 32 + l31;
        const char* efbase = (const char*)(efp + (size_t)((b * PTS + p) * HW) * Cc)
                             + l31 * 16;
        #pragma unroll
        for (int i2 = 0; i2 < 8; i2 += 2) {
            const int j = jb + i2 + lh;
            h2 a0 = (h2){0, 0}, a1 = (h2){0, 0}, a2 = (h2){0, 0}, a3 = (h2){0, 0};
            #pragma unroll
            for (int u = 0; u < 20; u++) {
                unsigned wu = s_w[p][j][u];
                unsigned idx = s_o[p][j][u];
                uint4 v = *(const uint4*)(efbase + ((size_t)idx << 9));
                h2 wp = __builtin_bit_cast(h2, wu);
                a0 += wp * __builtin_bit_cast(h2, v.x);
                a1 += wp * __builtin_bit_cast(h2, v.y);
                a2 += wp * __builtin_bit_cast(h2, v.z);
                a3 += wp * __builtin_bit_cast(h2, v.w);
            }
            uint4 o = { __builtin_bit_cast(unsigned, a0), __builtin_bit_cast(unsigned, a1),
                        __builtin_bit_cast(unsigned, a2), __builtin_bit_cast(unsigned, a3) };
            *(uint4*)&Bs[j * 512 + ((g ^ j) << 3)] = o;
        }
    }
    __syncthreads();

    f32x16 acc;
    #pragma unroll
    for (int r = 0; r < 16; r++) acc[r] = 0.f;
    #pragma unroll 1
    for (int c4 = 0; c4 < 4; c4++) {
        hfrag A8[8];
        #pragma unroll
        for (int k8 = 0; k8 < 8; k8++)
            A8[k8] = *(const hfrag*)&wbm[(((c4 * 8 + k8) * 8 + wv) * 64 + ln) * 8];
        #pragma unroll
        for (int k8 = 0; k8 < 8; k8++) {
            int c = (c4 * 8 + k8) * 2 + lh;
            hfrag bf = *(const hfrag*)&Bs[l31 * 512 + ((c ^ l31) << 3)];
            acc = MFMA32(A8[k8], bf, acc);
        }
    }
    const int px = m0 + l31;
    float sg[4] = {0.f, 0.f, 0.f, 0.f};
    float qg[4] = {0.f, 0.f, 0.f, 0.f};
    #pragma unroll
    for (int q = 0; q < 4; q++) {
        float4 bv = *(const float4*)&mb[wv * 32 + q * 8 + 4 * lh];
        #pragma unroll
        for (int r = 0; r < 4; r++) {
            float bb = r == 0 ? bv.x : (r == 1 ? bv.y : (r == 2 ? bv.z : bv.w));
            float v = acc[q * 4 + r] + bb;
            int ch = wv * 32 + q * 8 + 4 * lh + r;
            mgb[((size_t)b * Cc + ch) * HW + px] = f2h(v);
            sg[q] += v; qg[q] += v * v;
        }
    }
    #pragma unroll
    for (int q = 0; q < 4; q++) {
        #pragma unroll
        for (int off = 1; off <= 32; off <<= 1) {
            sg[q] += __shfl_xor(sg[q], off);
            qg[q] += __shfl_xor(qg[q], off);
        }
    }
    if (ln == 0) {
        #pragma unroll
        for (int q = 0; q < 4; q++) {
            int g = wv * 4 + q;
            size_t idx = ((size_t)(b * 32 + g) * NTILE + tile) * 2;
            part2[idx + 0] = sg[q];
            part2[idx + 1] = qg[q];
        }
    }
}

__global__ __launch_bounds__(256)
void k_gnfinal(const float* __restrict__ part2, float* __restrict__ statf)
{
    const int bg = blockIdx.x;
    const int t = threadIdx.x;
    float s = 0.f, q = 0.f;
    for (int u = t; u < NTILE; u += 256) {
        s += part2[((size_t)bg * NTILE + u) * 2 + 0];
        q += part2[((size_t)bg * NTILE + u) * 2 + 1];
    }
    #pragma unroll
    for (int off = 1; off <= 32; off <<= 1) {
        s += __shfl_xor(s, off);
        q += __shfl_xor(q, off);
    }
    __shared__ float rs[4], rq[4];
    int wid = t >> 6;
    if ((t & 63) == 0) { rs[wid] = s; rq[wid] = q; }
    __syncthreads();
    if (t == 0) {
        float S = rs[0] + rs[1] + rs[2] + rs[3];
        float Q = rq[0] + rq[1] + rq[2] + rq[3];
        const float n = 8.f * HW;
        float mean = S / n;
        float var  = Q / n - mean * mean;
        statf[bg * 2 + 0] = mean;
        statf[bg * 2 + 1] = rsqrtf(var + GN_EPS);
    }
}

__global__ __launch_bounds__(256)
void k_gnapply(const ushort* __restrict__ mgb, const float* __restrict__ statf,
               const float* __restrict__ gg, const float* __restrict__ gb,
               float* __restrict__ out)
{
    const int i8 = blockIdx.x * 256 + threadIdx.x;
    const int i = i8 * 8;
    const int CHW = Cc * HW;
    const int b = i / CHW;
    const int r = i - b * CHW;
    const int c = r / HW;
    const int g = c >> 3;
    float mean = statf[(b * 32 + g) * 2 + 0];
    float istd = statf[(b * 32 + g) * 2 + 1];
    float sc = istd * gg[c];
    float sh = gb[c] - mean * sc;
    uint4 v = *(const uint4*)(mgb + i);
    float4 o0, o1;
    o0.x = fmaxf(hlo(v.x) * sc + sh, 0.f);
    o0.y = fmaxf(hhi(v.x) * sc + sh, 0.f);
    o0.z = fmaxf(hlo(v.y) * sc + sh, 0.f);
    o0.w = fmaxf(hhi(v.y) * sc + sh, 0.f);
    o1.x = fmaxf(hlo(v.z) * sc + sh, 0.f);
    o1.y = fmaxf(hhi(v.z) * sc + sh, 0.f);
    o1.z = fmaxf(hlo(v.w) * sc + sh, 0.f);
    o1.w = fmaxf(hhi(v.w) * sc + sh, 0.f);
    *(float4*)(out + i)     = o0;
    *(float4*)(out + i + 4) = o1;
}

// ---------------------------------------------------------------------------
extern "C" void kernel_launch(void* const* d_in, const int* in_sizes, int n_in,
                              void* d_out, int out_size, void* d_ws, size_t ws_size,
                              hipStream_t stream)
{
    const float* x    = (const float*)d_in[0];
    const float* offs = (const float*)d_in[1];
    const float* efw  = (const float*)d_in[2];
    const float* efb  = (const float*)d_in[3];
    const float* w1   = (const float*)d_in[4];
    const float* b1   = (const float*)d_in[5];
    const float* w2   = (const float*)d_in[6];
    const float* b2   = (const float*)d_in[7];
    const float* mw   = (const float*)d_in[8];
    const float* mb   = (const float*)d_in[9];
    const float* gg   = (const float*)d_in[10];
    const float* gb   = (const float*)d_in[11];
    float* out = (float*)d_out;

    ushort* wb    = (ushort*)d_ws;
    ushort* wbe   = wb;                          // 131072 (frag order)
    ushort* wb1   = wb + 131072;
    ushort* wbm   = wb + 262144;
    ushort* efp   = wb + 393216;                        // B*P*HW*C fp16
    ushort* xbt   = efp + (size_t)Bx * PTS * HW * Cc;   // B*HW*C fp16
    ushort* mgb   = xbt + (size_t)Bx * HW * Cc;         // B*C*HW fp16 (fallback)
    float*  heat  = (float*)(mgb + (size_t)Bx * Cc * HW);
    float*  part2 = heat + (size_t)Bx * PTS * HW;       // 64*NTILE*2 floats
    float*  statf = part2 + (size_t)64 * NTILE * 2;     // 128 floats

    dim3 blk(256);
    k_pre    <<<dim3(7792),             blk, 0, stream>>>(efw, w1, mw, wb, x, xbt);
    k_ef     <<<dim3(119, Bx),    dim3(512), 0, stream>>>(xbt, wbe, efb, efp);
    k_heat   <<<dim3(119, 4),     dim3(512), 0, stream>>>(efp, wb1, b1, w2, b2, heat);

    const ushort* efp_c = efp;
    const float*  heat_c = heat;
    void* args[] = { (void*)&efp_c, (void*)&heat_c, (void*)&offs, (void*)&wbm,
                     (void*)&mb, (void*)&gg, (void*)&gb, (void*)&part2,
                     (void*)&statf, (void*)&out };
    hipError_t e = hipLaunchCooperativeKernel((const void*)k_smgn, dim3(952),
                                              dim3(512), args, 0, stream);
    if (e != hipSuccess) {
        // fallback: proven R9 three-kernel path
        k_sm     <<<dim3(952),     dim3(512), 0, stream>>>(efp, heat, offs, wbm, mb, mgb, part2);
        k_gnfinal<<<dim3(64),            blk, 0, stream>>>(part2, statf);
        k_gnapply<<<dim3(Bx * Cc * HW / 8 / 256), blk, 0, stream>>>(mgb, statf, gg, gb, out);
    }
}

// Round 11
// 192.630 us; speedup vs baseline: 2.3777x; 2.3777x over previous
//
#include <hip/hip_runtime.h>

#define BINS 5
#define PTS  2
constexpr int Bx = 2, Cc = 256, Hh = 100, Ww = 152;
constexpr int HW = Hh * Ww;          // 15200
constexpr int NTILE = 475;           // 32-px tiles (exact)
constexpr float EPS_DIV = 1e-6f;
constexpr float GN_EPS  = 1e-5f;

typedef __attribute__((ext_vector_type(8)))  _Float16 hfrag;  // 8 fp16
typedef __attribute__((ext_vector_type(2)))  _Float16 h2;
typedef __attribute__((ext_vector_type(16))) float    f32x16; // 32x32 MFMA C/D

__device__ __forceinline__ ushort f2h(float f) {
    return __builtin_bit_cast(ushort, (_Float16)f);
}
__device__ __forceinline__ float hlo(unsigned u) {
    return (float)__builtin_bit_cast(_Float16, (ushort)(u & 0xffffu));
}
__device__ __forceinline__ float hhi(unsigned u) {
    return (float)__builtin_bit_cast(_Float16, (ushort)(u >> 16));
}

#define GLL16(g, l) __builtin_amdgcn_global_load_lds( \
    (const __attribute__((address_space(1))) unsigned*)(g), \
    (__attribute__((address_space(3))) unsigned*)(l), 16, 0, 0)

#define MFMA32(a, b, c) __builtin_amdgcn_mfma_f32_32x32x16_f16(a, b, c, 0, 0, 0)
#define SB0() __builtin_amdgcn_sched_barrier(0)

// ---------------------------------------------------------------------------
// K0: fused preprocessing.  Blocks 0..191: weight convert to fp16 in
// 32x32x16-MFMA fragment order.  Blocks 192..7791: x transpose+convert.
// ---------------------------------------------------------------------------
__global__ __launch_bounds__(256)
void k_pre(const float* __restrict__ efw, const float* __restrict__ w1,
           const float* __restrict__ mw, ushort* __restrict__ wb,
           const float* __restrict__ x, ushort* __restrict__ xbt)
{
    __shared__ float tile[32][33];
    const int bid = blockIdx.x;
    const int t = threadIdx.x;
    if (bid < 192) {
        int gid = bid * 256 + t;
        int i = gid * 8;
        int arr = i >> 17, off = i & 131071;
        const float* src = arr == 0 ? efw : (arr == 1 ? w1 : mw);
        float4 v0 = *(const float4*)(src + off);
        float4 v1 = *(const float4*)(src + off + 4);
        int outaddr;
        if (arr == 0) {                // ef_w: M=512, K=256
            int m = off >> 8, k = off & 255;
            outaddr = (((k >> 4) * 16 + (m >> 5)) * 64 + (m & 31) + 32 * ((k >> 3) & 1)) * 8;
        } else if (arr == 1) {         // hm1_w: per p, M=256, K=256
            int p = off >> 16, r = off & 65535;
            int m = r >> 8, k = r & 255;
            outaddr = p * 65536 +
                      (((k >> 4) * 8 + (m >> 5)) * 64 + (m & 31) + 32 * ((k >> 3) & 1)) * 8;
        } else {                       // merge_w: M=256, K=512
            int m = off >> 9, k = off & 511;
            outaddr = (((k >> 4) * 8 + (m >> 5)) * 64 + (m & 31) + 32 * ((k >> 3) & 1)) * 8;
        }
        ushort o[8] = { f2h(v0.x), f2h(v0.y), f2h(v0.z), f2h(v0.w),
                        f2h(v1.x), f2h(v1.y), f2h(v1.z), f2h(v1.w) };
        *(uint4*)(wb + arr * 131072 + outaddr) = *(uint4*)o;
    } else {
        int r = bid - 192;             // 0..7599
        const int b = r / 3800; r -= b * 3800;
        const int c0 = (r / 475) * 32;
        const int hw0 = (r % 475) * 32;
        const float* xb = x + ((size_t)b * Cc + c0) * HW + hw0;
        const int tx = t & 31, ty = t >> 5;
        #pragma unroll
        for (int rr = 0; rr < 4; rr++) {
            int c = ty + rr * 8;
            tile[c][tx] = xb[(size_t)c * HW + tx];
        }
        __syncthreads();
        const int hwl = t >> 3, c4 = (t & 7) * 4;
        ushort4 o = { f2h(tile[c4 + 0][hwl]), f2h(tile[c4 + 1][hwl]),
                      f2h(tile[c4 + 2][hwl]), f2h(tile[c4 + 3][hwl]) };
        *(ushort4*)&xbt[((size_t)b * HW + hw0 + hwl) * Cc + c0 + c4] = o;
    }
}

// ---------------------------------------------------------------------------
// K1: efp = ef_w @ x + ef_b.  A (512x256) in registers, LDS = B only
// (2 x 32KB dbuf), 32x32x16 MFMA, counted vmcnt.  (proven R3)
// ---------------------------------------------------------------------------
__global__ __launch_bounds__(512, 2)
void k_ef(const ushort* __restrict__ xbt, const ushort* __restrict__ wbe,
          const float* __restrict__ efb, ushort* __restrict__ efp)
{
    __shared__ ushort B0[64 * 256];
    __shared__ ushort B1[64 * 256];
    const int t = threadIdx.x;
    const int wv = t >> 6, ln = t & 63;
    const int l31 = ln & 31, lh = ln >> 5;
    const int b = blockIdx.y;
    const int tt0 = blockIdx.x * 2;
    const ushort* xb = xbt + (size_t)b * HW * Cc;

    hfrag A[2][16];
    #pragma unroll
    for (int mf = 0; mf < 2; mf++)
        #pragma unroll
        for (int ks = 0; ks < 16; ks++)
            A[mf][ks] = *(const hfrag*)&wbe[((ks * 16 + (wv * 2 + mf)) * 64 + ln) * 8];
    SB0();

    auto stageB = [&](int tt, ushort* dst) {
        int tp0 = tt * 64;
        #pragma unroll
        for (int j = 0; j < 4; j++) {
            int unit = j * 512 + t;
            int prow = unit >> 5, c8 = unit & 31;
            int pq = tp0 + prow; if (pq > HW - 1) pq = HW - 1;
            const ushort* g = xb + (size_t)pq * Cc + ((c8 ^ (prow & 7)) << 3);
            ushort* l = dst + (j * 512 + wv * 64) * 8;
            GLL16(g, l);
        }
    };
    stageB(tt0, B0);
    stageB(tt0 + 1, B1);
    SB0();
    asm volatile("s_waitcnt vmcnt(4)" ::: "memory");
    __builtin_amdgcn_s_barrier();
    SB0();

    auto compute = [&](int tt, const ushort* Bs) {
        f32x16 acc[2][2];
        #pragma unroll
        for (int mf = 0; mf < 2; mf++)
            #pragma unroll
            for (int pf = 0; pf < 2; pf++)
                #pragma unroll
                for (int r = 0; r < 16; r++) acc[mf][pf][r] = 0.f;
        #pragma unroll
        for (int ks = 0; ks < 16; ks++) {
            int c = ks * 2 + lh;
            #pragma unroll
            for (int pf = 0; pf < 2; pf++) {
                hfrag bf = *(const hfrag*)&Bs[(pf * 32 + l31) * 256 + ((c ^ (l31 & 7)) << 3)];
                acc[0][pf] = MFMA32(A[0][ks], bf, acc[0][pf]);
                acc[1][pf] = MFMA32(A[1][ks], bf, acc[1][pf]);
            }
        }
        const int tp0 = tt * 64;
        #pragma unroll
        for (int mf = 0; mf < 2; mf++) {
            int m0 = wv * 2 + mf;
            const int p_ = m0 >> 3;
            ushort* outb = efp + (size_t)((b * PTS + p_) * HW) * Cc;
            int chb = (m0 * 32) & 255;
            #pragma unroll
            for (int q = 0; q < 4; q++) {
                float4 bv = *(const float4*)&efb[m0 * 32 + q * 8 + 4 * lh];
                #pragma unroll
                for (int pf = 0; pf < 2; pf++) {
                    int px = tp0 + pf * 32 + l31;
                    if (px < HW) {
                        int ch = chb + q * 8 + 4 * lh;
                        ushort4 o = { f2h(acc[mf][pf][q * 4 + 0] + bv.x),
                                      f2h(acc[mf][pf][q * 4 + 1] + bv.y),
                                      f2h(acc[mf][pf][q * 4 + 2] + bv.z),
                                      f2h(acc[mf][pf][q * 4 + 3] + bv.w) };
                        *(ushort4*)&outb[(size_t)px * Cc + ch] = o;
                    }
                }
            }
        }
    };
    compute(tt0, B0);
    asm volatile("s_waitcnt vmcnt(0)" ::: "memory");
    __builtin_amdgcn_s_barrier();
    SB0();
    compute(tt0 + 1, B1);
}

// ---------------------------------------------------------------------------
// K2: heat = exp(w2.relu(w1@efp + b1) + b2) fused (proven R3)
// ---------------------------------------------------------------------------
__global__ __launch_bounds__(512, 2)
void k_heat(const ushort* __restrict__ efp, const ushort* __restrict__ wb1,
            const float* __restrict__ b1, const float* __restrict__ w2,
            const float* __restrict__ b2, float* __restrict__ heat)
{
    __shared__ ushort B0[64 * 256];
    __shared__ ushort B1[64 * 256];
    __shared__ float red[8][64];
    const int t = threadIdx.x;
    const int wv = t >> 6, ln = t & 63;
    const int l31 = ln & 31, lh = ln >> 5;
    const int zz = blockIdx.y;
    const int b = zz >> 1, p = zz & 1;
    const int tt0 = blockIdx.x * 2;
    const ushort* eb = efp + (size_t)((b * PTS + p) * HW) * Cc;
    const float* b1p = b1 + p * 256;
    const float* w2p = w2 + p * 256;
    const float b2v = b2[p];

    hfrag A[16];
    #pragma unroll
    for (int ks = 0; ks < 16; ks++)
        A[ks] = *(const hfrag*)&wb1[p * 65536 + ((ks * 8 + wv) * 64 + ln) * 8];
    SB0();

    auto stageB = [&](int tt, ushort* dst) {
        int tp0 = tt * 64;
        #pragma unroll
        for (int j = 0; j < 4; j++) {
            int unit = j * 512 + t;
            int prow = unit >> 5, c8 = unit & 31;
            int pq = tp0 + prow; if (pq > HW - 1) pq = HW - 1;
            const ushort* g = eb + (size_t)pq * Cc + ((c8 ^ (prow & 7)) << 3);
            ushort* l = dst + (j * 512 + wv * 64) * 8;
            GLL16(g, l);
        }
    };
    stageB(tt0, B0);
    stageB(tt0 + 1, B1);
    SB0();
    asm volatile("s_waitcnt vmcnt(4)" ::: "memory");
    __builtin_amdgcn_s_barrier();
    SB0();

    auto compute = [&](int tt, const ushort* Bs) {
        f32x16 acc[2];
        #pragma unroll
        for (int pf = 0; pf < 2; pf++)
            #pragma unroll
            for (int r = 0; r < 16; r++) acc[pf][r] = 0.f;
        #pragma unroll
        for (int ks = 0; ks < 16; ks++) {
            int c = ks * 2 + lh;
            #pragma unroll
            for (int pf = 0; pf < 2; pf++) {
                hfrag bf = *(const hfrag*)&Bs[(pf * 32 + l31) * 256 + ((c ^ (l31 & 7)) << 3)];
                acc[pf] = MFMA32(A[ks], bf, acc[pf]);
            }
        }
        float s[2] = {0.f, 0.f};
        #pragma unroll
        for (int q = 0; q < 4; q++) {
            float4 b1v = *(const float4*)&b1p[wv * 32 + q * 8 + 4 * lh];
            float4 w2v = *(const float4*)&w2p[wv * 32 + q * 8 + 4 * lh];
            #pragma unroll
            for (int pf = 0; pf < 2; pf++) {
                float h0 = acc[pf][q * 4 + 0] + b1v.x;
                float h1 = acc[pf][q * 4 + 1] + b1v.y;
                float h2_ = acc[pf][q * 4 + 2] + b1v.z;
                float h3 = acc[pf][q * 4 + 3] + b1v.w;
                s[pf] += w2v.x * (h0 > 0.f ? h0 : 0.f);
                s[pf] += w2v.y * (h1 > 0.f ? h1 : 0.f);
                s[pf] += w2v.z * (h2_ > 0.f ? h2_ : 0.f);
                s[pf] += w2v.w * (h3 > 0.f ? h3 : 0.f);
            }
        }
        s[0] += __shfl_xor(s[0], 32);
        s[1] += __shfl_xor(s[1], 32);
        if (lh == 0) {
            red[wv][l31]      = s[0];
            red[wv][32 + l31] = s[1];
        }
        asm volatile("s_waitcnt lgkmcnt(0)" ::: "memory");
        __builtin_amdgcn_s_barrier();
        if (t < 64) {
            float v = red[0][t] + red[1][t] + red[2][t] + red[3][t] +
                      red[4][t] + red[5][t] + red[6][t] + red[7][t];
            int px = tt * 64 + t;
            if (px < HW) heat[(size_t)(b * PTS + p) * HW + px] = expf(v + b2v);
        }
    };
    compute(tt0, B0);
    asm volatile("s_waitcnt vmcnt(0)" ::: "memory");
    __builtin_amdgcn_s_barrier();
    SB0();
    compute(tt0 + 1, B1);
}

// ---------------------------------------------------------------------------
// K3: FUSED sampling + merge.  Phase-3 gather: forced 4-batch x 5-load
// software pipeline (sched_barrier fences; R9-proven best: 44.7 us, FETCH
// 21.5 MB).  XCD-batch partition keeps each XCD's gather set L2-resident.
// ---------------------------------------------------------------------------
__global__ __launch_bounds__(512, 4)
void k_sm(const ushort* __restrict__ efp, const float* __restrict__ heat,
          const float* __restrict__ offs, const ushort* __restrict__ wbm,
          const float* __restrict__ mb, ushort* __restrict__ mgb,
          float* __restrict__ part2)
{
    __shared__ ushort Bs[32 * 512];       // 32768 B sampled tile [px][512]
    __shared__ unsigned s_w[2][32][20];   // 5120 B: f32 weight -> fp16 pair
    __shared__ ushort   s_o[2][32][20];   // 2560 B: sample row index
    const int t = threadIdx.x;
    const int wv = t >> 6, ln = t & 63;
    const int l31 = ln & 31, lh = ln >> 5;
    // XCD-batch partition (verified R8: FETCH 41->27 MB): bid%8 = XCD;
    // XCDs 0-3 own b=0, 4-7 own b=1; contiguous 119-tile strip per XCD.
    const int bid = blockIdx.x;
    const int xcd = bid & 7, ii = bid >> 3;          // ii in 0..118
    const int b = xcd >> 2;
    const int tile = (xcd & 3) * 119 + ii;
    if (tile >= NTILE) return;                       // 2 idle blocks
    const int m0 = tile * 32;

    // ---- phase 1: bilinear weights for both p (320 threads) ----
    if (t < 32 * BINS * PTS) {
        int p = t / 160, r = t - p * 160;
        int j = r / BINS, k = r - (r / BINS) * BINS;
        int hw = m0 + j;
        int hh = hw / Ww, ww = hw - hh * Ww;
        const float* heat_bp = heat + (size_t)(b * PTS + p) * HW;
        int chy = (p * BINS + k) * 2;
        float oy = offs[((size_t)b * (PTS * BINS * 2) + chy)     * HW + hw];
        float ox = offs[((size_t)b * (PTS * BINS * 2) + chy + 1) * HW + hw];
        float ysf = (float)hh + oy;
        float xsf = (float)ww + ox;
        float y0 = floorf(ysf), x0 = floorf(xsf);
        #pragma unroll
        for (int dy = 0; dy < 2; dy++)
            #pragma unroll
            for (int dx = 0; dx < 2; dx++) {
                float yi = y0 + dy, xi = x0 + dx;
                float wgt = (1.f - fabsf(ysf - yi)) * (1.f - fabsf(xsf - xi));
                bool valid = (yi >= 0.f) && (yi <= (float)(Hh - 1)) &&
                             (xi >= 0.f) && (xi <= (float)(Ww - 1));
                int yc = (int)yi; yc = yc < 0 ? 0 : (yc > Hh - 1 ? Hh - 1 : yc);
                int xc = (int)xi; xc = xc < 0 ? 0 : (xc > Ww - 1 ? Ww - 1 : xc);
                int idx = yc * Ww + xc;
                float wh = valid ? wgt * heat_bp[idx] : 0.f;
                int slot = k * 4 + dy * 2 + dx;
                s_w[p][j][slot] = __float_as_uint(wh);
                s_o[p][j][slot] = (ushort)idx;
            }
    }
    __syncthreads();
    // ---- phase 2: normalize + pack fp16 pair (64 threads) ----
    if (t < 64) {
        int p = t >> 5, px = t & 31;
        float s = 0.f;
        #pragma unroll
        for (int u = 0; u < 20; u++) s += __uint_as_float(s_w[p][px][u]);
        float inv = 1.f / (s + EPS_DIV);
        #pragma unroll
        for (int u = 0; u < 20; u++) {
            float w = __uint_as_float(s_w[p][px][u]) * inv;
            unsigned hw16 = (unsigned)f2h(w);
            s_w[p][px][u] = hw16 | (hw16 << 16);
        }
    }
    __syncthreads();

    // ---- phase 3: gather, forced 4x5 pipelined batches ----
    {
        const int p = wv >> 2;
        const int jb = (wv & 3) * 8;
        const int g = p * 32 + l31;          // column unit (16B) in [0,64)
        const char* efbase = (const char*)(efp + (size_t)((b * PTS + p) * HW) * Cc)
                             + l31 * 16;
        #pragma unroll 1
        for (int i2 = 0; i2 < 8; i2 += 2) {
            const int j = jb + i2 + lh;
            h2 a0 = (h2){0, 0}, a1 = (h2){0, 0}, a2 = (h2){0, 0}, a3 = (h2){0, 0};
            uint4 vA[5], vB[5];
            unsigned wA[5], wB[5];
            // issue batch 0 (u = 0..4)
            #pragma unroll
            for (int u = 0; u < 5; u++) {
                wA[u] = s_w[p][j][u];
                vA[u] = *(const uint4*)(efbase + ((size_t)s_o[p][j][u] << 9));
            }
            SB0();
            // issue batch 1 (u = 5..9)
            #pragma unroll
            for (int u = 0; u < 5; u++) {
                wB[u] = s_w[p][j][5 + u];
                vB[u] = *(const uint4*)(efbase + ((size_t)s_o[p][j][5 + u] << 9));
            }
            SB0();
            // consume batch 0
            #pragma unroll
            for (int u = 0; u < 5; u++) {
                h2 wp = __builtin_bit_cast(h2, wA[u]);
                a0 += wp * __builtin_bit_cast(h2, vA[u].x);
                a1 += wp * __builtin_bit_cast(h2, vA[u].y);
                a2 += wp * __builtin_bit_cast(h2, vA[u].z);
                a3 += wp * __builtin_bit_cast(h2, vA[u].w);
            }
            SB0();
            // issue batch 2 (u = 10..14) into vA
            #pragma unroll
            for (int u = 0; u < 5; u++) {
                wA[u] = s_w[p][j][10 + u];
                vA[u] = *(const uint4*)(efbase + ((size_t)s_o[p][j][10 + u] << 9));
            }
            SB0();
            // consume batch 1
            #pragma unroll
            for (int u = 0; u < 5; u++) {
                h2 wp = __builtin_bit_cast(h2, wB[u]);
                a0 += wp * __builtin_bit_cast(h2, vB[u].x);
                a1 += wp * __builtin_bit_cast(h2, vB[u].y);
                a2 += wp * __builtin_bit_cast(h2, vB[u].z);
                a3 += wp * __builtin_bit_cast(h2, vB[u].w);
            }
            SB0();
            // issue batch 3 (u = 15..19) into vB
            #pragma unroll
            for (int u = 0; u < 5; u++) {
                wB[u] = s_w[p][j][15 + u];
                vB[u] = *(const uint4*)(efbase + ((size_t)s_o[p][j][15 + u] << 9));
            }
            SB0();
            // consume batch 2
            #pragma unroll
            for (int u = 0; u < 5; u++) {
                h2 wp = __builtin_bit_cast(h2, wA[u]);
                a0 += wp * __builtin_bit_cast(h2, vA[u].x);
                a1 += wp * __builtin_bit_cast(h2, vA[u].y);
                a2 += wp * __builtin_bit_cast(h2, vA[u].z);
                a3 += wp * __builtin_bit_cast(h2, vA[u].w);
            }
            SB0();
            // consume batch 3
            #pragma unroll
            for (int u = 0; u < 5; u++) {
                h2 wp = __builtin_bit_cast(h2, wB[u]);
                a0 += wp * __builtin_bit_cast(h2, vB[u].x);
                a1 += wp * __builtin_bit_cast(h2, vB[u].y);
                a2 += wp * __builtin_bit_cast(h2, vB[u].z);
                a3 += wp * __builtin_bit_cast(h2, vB[u].w);
            }
            uint4 o = { __builtin_bit_cast(unsigned, a0), __builtin_bit_cast(unsigned, a1),
                        __builtin_bit_cast(unsigned, a2), __builtin_bit_cast(unsigned, a3) };
            *(uint4*)&Bs[j * 512 + ((g ^ j) << 3)] = o;
        }
    }
    __syncthreads();

    // ---- phase 4: merge GEMM (M=256, N=32, K=512); A streamed from L2 ----
    f32x16 acc;
    #pragma unroll
    for (int r = 0; r < 16; r++) acc[r] = 0.f;
    #pragma unroll 1
    for (int c4 = 0; c4 < 4; c4++) {
        hfrag A8[8];
        #pragma unroll
        for (int k8 = 0; k8 < 8; k8++)
            A8[k8] = *(const hfrag*)&wbm[(((c4 * 8 + k8) * 8 + wv) * 64 + ln) * 8];
        #pragma unroll
        for (int k8 = 0; k8 < 8; k8++) {
            int c = (c4 * 8 + k8) * 2 + lh;
            hfrag bf = *(const hfrag*)&Bs[l31 * 512 + ((c ^ l31) << 3)];
            acc = MFMA32(A8[k8], bf, acc);
        }
    }

    const int px = m0 + l31;                 // always < HW (475*32 = 15200)
    float sg[4] = {0.f, 0.f, 0.f, 0.f};
    float qg[4] = {0.f, 0.f, 0.f, 0.f};
    #pragma unroll
    for (int q = 0; q < 4; q++) {
        float4 bv = *(const float4*)&mb[wv * 32 + q * 8 + 4 * lh];
        #pragma unroll
        for (int r = 0; r < 4; r++) {
            float bb = r == 0 ? bv.x : (r == 1 ? bv.y : (r == 2 ? bv.z : bv.w));
            float v = acc[q * 4 + r] + bb;
            int ch = wv * 32 + q * 8 + 4 * lh + r;
            mgb[((size_t)b * Cc + ch) * HW + px] = f2h(v);
            sg[q] += v; qg[q] += v * v;
        }
    }
    #pragma unroll
    for (int q = 0; q < 4; q++) {
        #pragma unroll
        for (int off = 1; off <= 32; off <<= 1) {
            sg[q] += __shfl_xor(sg[q], off);
            qg[q] += __shfl_xor(qg[q], off);
        }
    }
    if (ln == 0) {
        #pragma unroll
        for (int q = 0; q < 4; q++) {
            int g = wv * 4 + q;
            size_t idx = ((size_t)(b * 32 + g) * NTILE + tile) * 2;
            part2[idx + 0] = sg[q];
            part2[idx + 1] = qg[q];
        }
    }
}

// ---------------------------------------------------------------------------
// K5: reduce per-tile GN partials -> mean/istd per (b,group)
// ---------------------------------------------------------------------------
__global__ __launch_bounds__(256)
void k_gnfinal(const float* __restrict__ part2, float* __restrict__ statf)
{
    const int bg = blockIdx.x;
    const int t = threadIdx.x;
    float s = 0.f, q = 0.f;
    for (int u = t; u < NTILE; u += 256) {
        s += part2[((size_t)bg * NTILE + u) * 2 + 0];
        q += part2[((size_t)bg * NTILE + u) * 2 + 1];
    }
    #pragma unroll
    for (int off = 1; off <= 32; off <<= 1) {
        s += __shfl_xor(s, off);
        q += __shfl_xor(q, off);
    }
    __shared__ float rs[4], rq[4];
    int wid = t >> 6;
    if ((t & 63) == 0) { rs[wid] = s; rq[wid] = q; }
    __syncthreads();
    if (t == 0) {
        float S = rs[0] + rs[1] + rs[2] + rs[3];
        float Q = rq[0] + rq[1] + rq[2] + rq[3];
        const float n = 8.f * HW;
        float mean = S / n;
        float var  = Q / n - mean * mean;
        statf[bg * 2 + 0] = mean;
        statf[bg * 2 + 1] = rsqrtf(var + GN_EPS);
    }
}

// ---------------------------------------------------------------------------
// K6: apply GN scale/shift + ReLU
// ---------------------------------------------------------------------------
__global__ __launch_bounds__(256)
void k_gnapply(const ushort* __restrict__ mgb, const float* __restrict__ statf,
               const float* __restrict__ gg, const float* __restrict__ gb,
               float* __restrict__ out)
{
    const int i8 = blockIdx.x * 256 + threadIdx.x;
    const int i = i8 * 8;
    const int CHW = Cc * HW;
    const int b = i / CHW;
    const int r = i - b * CHW;
    const int c = r / HW;
    const int g = c >> 3;
    float mean = statf[(b * 32 + g) * 2 + 0];
    float istd = statf[(b * 32 + g) * 2 + 1];
    float sc = istd * gg[c];
    float sh = gb[c] - mean * sc;
    uint4 v = *(const uint4*)(mgb + i);
    float4 o0, o1;
    o0.x = fmaxf(hlo(v.x) * sc + sh, 0.f);
    o0.y = fmaxf(hhi(v.x) * sc + sh, 0.f);
    o0.z = fmaxf(hlo(v.y) * sc + sh, 0.f);
    o0.w = fmaxf(hhi(v.y) * sc + sh, 0.f);
    o1.x = fmaxf(hlo(v.z) * sc + sh, 0.f);
    o1.y = fmaxf(hhi(v.z) * sc + sh, 0.f);
    o1.z = fmaxf(hlo(v.w) * sc + sh, 0.f);
    o1.w = fmaxf(hhi(v.w) * sc + sh, 0.f);
    *(float4*)(out + i)     = o0;
    *(float4*)(out + i + 4) = o1;
}

// ---------------------------------------------------------------------------
extern "C" void kernel_launch(void* const* d_in, const int* in_sizes, int n_in,
                              void* d_out, int out_size, void* d_ws, size_t ws_size,
                              hipStream_t stream)
{
    const float* x    = (const float*)d_in[0];
    const float* offs = (const float*)d_in[1];
    const float* efw  = (const float*)d_in[2];
    const float* efb  = (const float*)d_in[3];
    const float* w1   = (const float*)d_in[4];
    const float* b1   = (const float*)d_in[5];
    const float* w2   = (const float*)d_in[6];
    const float* b2   = (const float*)d_in[7];
    const float* mw   = (const float*)d_in[8];
    const float* mb   = (const float*)d_in[9];
    const float* gg   = (const float*)d_in[10];
    const float* gb   = (const float*)d_in[11];
    float* out = (float*)d_out;

    ushort* wb    = (ushort*)d_ws;
    ushort* wbe   = wb;                          // 131072 (frag order)
    ushort* wb1   = wb + 131072;
    ushort* wbm   = wb + 262144;
    ushort* efp   = wb + 393216;                        // B*P*HW*C fp16
    ushort* xbt   = efp + (size_t)Bx * PTS * HW * Cc;   // B*HW*C fp16
    ushort* mgb   = xbt + (size_t)Bx * HW * Cc;         // B*C*HW fp16
    float*  heat  = (float*)(mgb + (size_t)Bx * Cc * HW);
    float*  part2 = heat + (size_t)Bx * PTS * HW;       // 64*NTILE*2 floats
    float*  statf = part2 + (size_t)64 * NTILE * 2;     // 128 floats

    dim3 blk(256);
    k_pre    <<<dim3(7792),             blk, 0, stream>>>(efw, w1, mw, wb, x, xbt);
    k_ef     <<<dim3(119, Bx),    dim3(512), 0, stream>>>(xbt, wbe, efb, efp);
    k_heat   <<<dim3(119, 4),     dim3(512), 0, stream>>>(efp, wb1, b1, w2, b2, heat);
    k_sm     <<<dim3(952),        dim3(512), 0, stream>>>(efp, heat, offs, wbm, mb, mgb, part2);
    k_gnfinal<<<dim3(64),               blk, 0, stream>>>(part2, statf);
    k_gnapply<<<dim3(Bx * Cc * HW / 8 / 256), blk, 0, stream>>>(mgb, statf, gg, gb, out);
}